// Round 4
// baseline (349.581 us; speedup 1.0000x reference)
//
#include <hip/hip_runtime.h>

// GCN 3-layer forward on MI355X — round 4: fully-fused bf16 pipeline.
//
// Identity: invd = rsd^2, so self term H_i*invd_i = rsd_i * Hb_i (Hb = bf16(H*rsd)).
// Every layer output = relu(b + rsd_i*(Hb_i + sum_e Hb[col_e])) — no f32 partial
// buffer needed. Pipeline:
//   GEMM1 (x@W1 -> Hb1, bf16 only)
//   fused agg+GEMM2 (gather Hb1 -> LDS X tile (bias+relu, f32) -> @W2 -> Hb2)
//   fused agg+GEMM3 (gather Hb2 -> LDS -> @W3 -> Hb3, COUT=64)
//   final agg (gather Hb3 + bias -> d_out f32)
// Eliminates ~205 MB of f32 activation round-trips and 3 dispatches vs R3.

#define K_DIM 128

__device__ __forceinline__ unsigned short f2bf(float x) {
    unsigned u = __float_as_uint(x);
    return (unsigned short)((u + 0x7fffu + ((u >> 16) & 1u)) >> 16);
}
__device__ __forceinline__ float bflo(unsigned v) { return __uint_as_float(v << 16); }
__device__ __forceinline__ float bfhi(unsigned v) { return __uint_as_float(v & 0xffff0000u); }

// ---------------- degree / CSR build ----------------

__global__ void k_zero_int(int* __restrict__ p, int n) {
    int i = blockIdx.x * 256 + threadIdx.x;
    if (i < n) p[i] = 0;
}

__global__ void k_count(const int* __restrict__ dst, int* __restrict__ cnt, int E) {
    int e = blockIdx.x * 256 + threadIdx.x;
    if (e < E) atomicAdd(&cnt[dst[e]], 1);
}

__global__ void k_norms(const int* __restrict__ cnt, float* __restrict__ rsd, int n) {
    int i = blockIdx.x * 256 + threadIdx.x;
    if (i < n) rsd[i] = rsqrtf((float)cnt[i] + 1.0f);   // +1 self-loop
}

__global__ void k_scan_block(const int* __restrict__ cnt, int* __restrict__ rowptr,
                             int* __restrict__ bsum, int n) {
    __shared__ int s[256];
    int t = threadIdx.x;
    int i = blockIdx.x * 256 + t;
    int x = (i < n) ? cnt[i] : 0;
    s[t] = x;
    __syncthreads();
#pragma unroll
    for (int d = 1; d < 256; d <<= 1) {
        int v = (t >= d) ? s[t - d] : 0;
        __syncthreads();
        s[t] += v;
        __syncthreads();
    }
    if (i < n) rowptr[i] = s[t] - x;        // exclusive
    if (t == 255) bsum[blockIdx.x] = s[255];
}

__global__ void k_scan_bsums(int* __restrict__ bsum, int nb) {
    __shared__ int s[256];
    int t = threadIdx.x;
    int x = (t < nb) ? bsum[t] : 0;
    s[t] = x;
    __syncthreads();
#pragma unroll
    for (int d = 1; d < 256; d <<= 1) {
        int v = (t >= d) ? s[t - d] : 0;
        __syncthreads();
        s[t] += v;
        __syncthreads();
    }
    if (t < nb) bsum[t] = s[t] - x;         // exclusive
}

__global__ void k_scan_add(int* __restrict__ rowptr, int* __restrict__ cursor,
                           const int* __restrict__ bsum, int n, int E) {
    int i = blockIdx.x * 256 + threadIdx.x;
    if (i < n) {
        int v = rowptr[i] + bsum[i >> 8];
        rowptr[i] = v;
        cursor[i] = v;
    }
    if (i == 0) rowptr[n] = E;
}

__global__ void k_fill(const int* __restrict__ src, const int* __restrict__ dst,
                       int* __restrict__ cursor, int* __restrict__ col, int E) {
    int e = blockIdx.x * 256 + threadIdx.x;
    if (e < E) {
        int d = dst[e];
        int pos = atomicAdd(&cursor[d], 1);
        col[pos] = src[e];
    }
}

// ---------------- GEMM1: Hb = bf16((X @ W) * rsd) ----------------
template <int COUT>
__launch_bounds__(256)
__global__ void k_gemm1(const float* __restrict__ X, const float* __restrict__ W,
                        const float* __restrict__ rsd,
                        unsigned short* __restrict__ Hb, int nrows) {
    constexpr int BM = 64, BK = 32, TN = 4;
    constexpr int CG = COUT / TN;
    constexpr int RG = 256 / CG;
    constexpr int TM = BM / RG;
    constexpr int BMP = 68;

    __shared__ float Xs[BK][BMP];
    __shared__ float Ws[BK][COUT];

    const int tid = threadIdx.x;
    const int tx = tid % CG;
    const int ty = tid / CG;
    const int r0 = blockIdx.x * BM;

    float acc[TM][TN];
#pragma unroll
    for (int i = 0; i < TM; ++i)
#pragma unroll
        for (int j = 0; j < TN; ++j) acc[i][j] = 0.0f;

    for (int kb = 0; kb < K_DIM; kb += BK) {
        __syncthreads();
        {
            int r = tid >> 3, kq = tid & 7;
#pragma unroll
            for (int p = 0; p < 2; ++p) {
                int rr = r + p * 32;
                int grow = r0 + rr;
                if (grow >= nrows) grow = nrows - 1;
                float4 v = *(const float4*)&X[(size_t)grow * K_DIM + kb + kq * 4];
                Xs[kq * 4 + 0][rr] = v.x;
                Xs[kq * 4 + 1][rr] = v.y;
                Xs[kq * 4 + 2][rr] = v.z;
                Xs[kq * 4 + 3][rr] = v.w;
            }
        }
        {
            constexpr int F4 = COUT / 4;
            constexpr int RP = 256 / F4;
            int wq = tid % F4, wr = tid / F4;
#pragma unroll
            for (int p = 0; p < BK / RP; ++p) {
                int krow = wr + p * RP;
                *(float4*)&Ws[krow][wq * 4] =
                    *(const float4*)&W[(size_t)(kb + krow) * COUT + wq * 4];
            }
        }
        __syncthreads();
#pragma unroll
        for (int kk = 0; kk < BK; ++kk) {
            float4 w4 = *(const float4*)&Ws[kk][tx * TN];
            float a[TM];
#pragma unroll
            for (int i = 0; i < TM; i += 4) {
                float4 a4 = *(const float4*)&Xs[kk][ty * TM + i];
                a[i] = a4.x; a[i + 1] = a4.y; a[i + 2] = a4.z; a[i + 3] = a4.w;
            }
#pragma unroll
            for (int i = 0; i < TM; ++i) {
                acc[i][0] += a[i] * w4.x;
                acc[i][1] += a[i] * w4.y;
                acc[i][2] += a[i] * w4.z;
                acc[i][3] += a[i] * w4.w;
            }
        }
    }

#pragma unroll
    for (int i = 0; i < TM; ++i) {
        int row = r0 + ty * TM + i;
        if (row < nrows) {
            float rs = rsd[row];
            ushort4 hb;
            hb.x = f2bf(acc[i][0] * rs);
            hb.y = f2bf(acc[i][1] * rs);
            hb.z = f2bf(acc[i][2] * rs);
            hb.w = f2bf(acc[i][3] * rs);
            *(ushort4*)&Hb[(size_t)row * COUT + tx * TN] = hb;
        }
    }
}

// ---------------- fused aggregate + GEMM ----------------
// Phase 1: X[rr,:] = relu(bias + rsd[row]*(Hb_in[row,:] + sum_e Hb_in[col,:]))
//          written transposed into LDS Xs[CIN][BMP] for the 64 rows of this block.
// Phase 2: Hb_out = bf16((X @ W) * rsd), W staged per BK=32 from global.
template <int COUT>
__launch_bounds__(256)
__global__ void k_agg_gemm(const unsigned short* __restrict__ Hb_in,
                           const int* __restrict__ rowptr, const int* __restrict__ col,
                           const float* __restrict__ rsd, const float* __restrict__ bias,
                           const float* __restrict__ W,
                           unsigned short* __restrict__ Hb_out, int nrows) {
    constexpr int BM = 64, BK = 32, TN = 4;
    constexpr int CG = COUT / TN;
    constexpr int RG = 256 / CG;
    constexpr int TM = BM / RG;
    constexpr int CIN = 128;
    constexpr int BMP = 68;

    __shared__ float Xs[CIN][BMP];   // full K-depth X tile, transposed
    __shared__ float Ws[BK][COUT];

    const int tid = threadIdx.x;
    const int r0 = blockIdx.x * BM;

    // ---- phase 1: aggregation into Xs ----
    {
        const int lr = tid >> 4;             // 0..15: row slot within pass
        const int lc = (tid & 15) * 8;       // channel base (8 bf16 per lane)
        const float4 bb0 = *(const float4*)&bias[lc];
        const float4 bb1 = *(const float4*)&bias[lc + 4];
        float ob[8] = { bb0.x, bb0.y, bb0.z, bb0.w, bb1.x, bb1.y, bb1.z, bb1.w };
#pragma unroll
        for (int p = 0; p < 4; ++p) {
            const int rr = p * 16 + lr;
            const int row = r0 + rr;
            const int rc = (row < nrows) ? row : (nrows - 1);
            float acc[8];
            {   // self-loop contribution
                uint4 v = *(const uint4*)&Hb_in[(size_t)rc * CIN + lc];
                acc[0] = bflo(v.x); acc[1] = bfhi(v.x);
                acc[2] = bflo(v.y); acc[3] = bfhi(v.y);
                acc[4] = bflo(v.z); acc[5] = bfhi(v.z);
                acc[6] = bflo(v.w); acc[7] = bfhi(v.w);
            }
            int e = rowptr[rc], end = rowptr[rc + 1];
            for (; e + 1 < end; e += 2) {
                int s0 = col[e], s1 = col[e + 1];
                uint4 v0 = *(const uint4*)&Hb_in[(size_t)s0 * CIN + lc];
                uint4 v1 = *(const uint4*)&Hb_in[(size_t)s1 * CIN + lc];
                acc[0] += bflo(v0.x); acc[1] += bfhi(v0.x);
                acc[2] += bflo(v0.y); acc[3] += bfhi(v0.y);
                acc[4] += bflo(v0.z); acc[5] += bfhi(v0.z);
                acc[6] += bflo(v0.w); acc[7] += bfhi(v0.w);
                acc[0] += bflo(v1.x); acc[1] += bfhi(v1.x);
                acc[2] += bflo(v1.y); acc[3] += bfhi(v1.y);
                acc[4] += bflo(v1.z); acc[5] += bfhi(v1.z);
                acc[6] += bflo(v1.w); acc[7] += bfhi(v1.w);
            }
            if (e < end) {
                int s0 = col[e];
                uint4 v0 = *(const uint4*)&Hb_in[(size_t)s0 * CIN + lc];
                acc[0] += bflo(v0.x); acc[1] += bfhi(v0.x);
                acc[2] += bflo(v0.y); acc[3] += bfhi(v0.y);
                acc[4] += bflo(v0.z); acc[5] += bfhi(v0.z);
                acc[6] += bflo(v0.w); acc[7] += bfhi(v0.w);
            }
            const float rs = rsd[rc];
#pragma unroll
            for (int j = 0; j < 8; ++j)
                Xs[lc + j][rr] = fmaxf(ob[j] + rs * acc[j], 0.0f);
        }
    }

    // ---- phase 2: GEMM Xs @ W ----
    const int tx = tid % CG;
    const int ty = tid / CG;
    float acc2[TM][TN];
#pragma unroll
    for (int i = 0; i < TM; ++i)
#pragma unroll
        for (int j = 0; j < TN; ++j) acc2[i][j] = 0.0f;

    for (int kb = 0; kb < CIN; kb += BK) {
        __syncthreads();   // first iter: phase1 done; later: Ws readers done
        {
            constexpr int F4 = COUT / 4;
            constexpr int RP = 256 / F4;
            int wq = tid % F4, wr = tid / F4;
#pragma unroll
            for (int p = 0; p < BK / RP; ++p) {
                int krow = wr + p * RP;
                *(float4*)&Ws[krow][wq * 4] =
                    *(const float4*)&W[(size_t)(kb + krow) * COUT + wq * 4];
            }
        }
        __syncthreads();
#pragma unroll
        for (int kk = 0; kk < BK; ++kk) {
            float4 w4 = *(const float4*)&Ws[kk][tx * TN];
            float a[TM];
#pragma unroll
            for (int i = 0; i < TM; i += 4) {
                float4 a4 = *(const float4*)&Xs[kb + kk][ty * TM + i];
                a[i] = a4.x; a[i + 1] = a4.y; a[i + 2] = a4.z; a[i + 3] = a4.w;
            }
#pragma unroll
            for (int i = 0; i < TM; ++i) {
                acc2[i][0] += a[i] * w4.x;
                acc2[i][1] += a[i] * w4.y;
                acc2[i][2] += a[i] * w4.z;
                acc2[i][3] += a[i] * w4.w;
            }
        }
    }

#pragma unroll
    for (int i = 0; i < TM; ++i) {
        int row = r0 + ty * TM + i;
        if (row < nrows) {
            float rs = rsd[row];
            ushort4 hb;
            hb.x = f2bf(acc2[i][0] * rs);
            hb.y = f2bf(acc2[i][1] * rs);
            hb.z = f2bf(acc2[i][2] * rs);
            hb.w = f2bf(acc2[i][3] * rs);
            *(ushort4*)&Hb_out[(size_t)row * COUT + tx * TN] = hb;
        }
    }
}

// ---------------- final aggregation (layer 3) -> f32 d_out ----------------
// OUT[i,:] = bias + rsd[i]*(Hb[i,:] + sum_e Hb[col,:])
template <int C>
__launch_bounds__(256)
__global__ void k_agg_final(const unsigned short* __restrict__ Hb,
                            const int* __restrict__ rowptr, const int* __restrict__ col,
                            const float* __restrict__ rsd, const float* __restrict__ bias,
                            float* __restrict__ OUT, int n) {
    constexpr int TPN = C / 8;            // 8 (C=64)
    constexpr int NPB = 256 / TPN;        // 32 nodes/block
    const int node = blockIdx.x * NPB + threadIdx.x / TPN;
    const int c = (threadIdx.x % TPN) * 8;
    if (node >= n) return;

    float acc[8];
    {   // self
        uint4 v = *(const uint4*)&Hb[(size_t)node * C + c];
        acc[0] = bflo(v.x); acc[1] = bfhi(v.x);
        acc[2] = bflo(v.y); acc[3] = bfhi(v.y);
        acc[4] = bflo(v.z); acc[5] = bfhi(v.z);
        acc[6] = bflo(v.w); acc[7] = bfhi(v.w);
    }
    int e = rowptr[node], end = rowptr[node + 1];
    for (; e + 1 < end; e += 2) {
        int s0 = col[e], s1 = col[e + 1];
        uint4 v0 = *(const uint4*)&Hb[(size_t)s0 * C + c];
        uint4 v1 = *(const uint4*)&Hb[(size_t)s1 * C + c];
        acc[0] += bflo(v0.x); acc[1] += bfhi(v0.x);
        acc[2] += bflo(v0.y); acc[3] += bfhi(v0.y);
        acc[4] += bflo(v0.z); acc[5] += bfhi(v0.z);
        acc[6] += bflo(v0.w); acc[7] += bfhi(v0.w);
        acc[0] += bflo(v1.x); acc[1] += bfhi(v1.x);
        acc[2] += bflo(v1.y); acc[3] += bfhi(v1.y);
        acc[4] += bflo(v1.z); acc[5] += bfhi(v1.z);
        acc[6] += bflo(v1.w); acc[7] += bfhi(v1.w);
    }
    if (e < end) {
        int s0 = col[e];
        uint4 v0 = *(const uint4*)&Hb[(size_t)s0 * C + c];
        acc[0] += bflo(v0.x); acc[1] += bfhi(v0.x);
        acc[2] += bflo(v0.y); acc[3] += bfhi(v0.y);
        acc[4] += bflo(v0.z); acc[5] += bfhi(v0.z);
        acc[6] += bflo(v0.w); acc[7] += bfhi(v0.w);
    }

    const float rs = rsd[node];
    const float4 b0 = *(const float4*)&bias[c];
    const float4 b1 = *(const float4*)&bias[c + 4];
    float* po = &OUT[(size_t)node * C + c];
    *(float4*)&po[0] = make_float4(b0.x + rs * acc[0], b0.y + rs * acc[1],
                                   b0.z + rs * acc[2], b0.w + rs * acc[3]);
    *(float4*)&po[4] = make_float4(b1.x + rs * acc[4], b1.y + rs * acc[5],
                                   b1.z + rs * acc[6], b1.w + rs * acc[7]);
}

// ---------------- launch ----------------

extern "C" void kernel_launch(void* const* d_in, const int* in_sizes, int n_in,
                              void* d_out, int out_size, void* d_ws, size_t ws_size,
                              hipStream_t stream) {
    const float* x  = (const float*)d_in[0];
    const int*   ei = (const int*)d_in[1];
    const float* W1 = (const float*)d_in[2];
    const float* b1 = (const float*)d_in[3];
    const float* W2 = (const float*)d_in[4];
    const float* b2 = (const float*)d_in[5];
    const float* W3 = (const float*)d_in[6];
    const float* b3 = (const float*)d_in[7];

    const int N = in_sizes[0] / K_DIM;   // 50000
    const int E = in_sizes[1] / 2;       // 640000
    const int* srcv = ei;
    const int* dstv = ei + E;

    char* ws = (char*)d_ws;
    size_t off = 0;
    auto alloc = [&](size_t bytes) {
        char* p = ws + off;
        off += (bytes + 255) & ~(size_t)255;
        return p;
    };
    int*   cnt    = (int*)alloc((size_t)N * 4);
    int*   rowptr = (int*)alloc((size_t)(N + 1) * 4);
    int*   cursor = (int*)alloc((size_t)N * 4);
    int*   bsum   = (int*)alloc(256 * 4);
    float* rsd    = (float*)alloc((size_t)N * 4);
    int*   col    = (int*)alloc((size_t)E * 4);
    unsigned short* Hb1 = (unsigned short*)alloc((size_t)N * 128 * 2);
    unsigned short* Hb2 = (unsigned short*)alloc((size_t)N * 128 * 2);
    unsigned short* Hb3 = (unsigned short*)alloc((size_t)N * 64 * 2);
    float* out = (float*)d_out;

    const int gN = (N + 255) / 256;
    const int gE = (E + 255) / 256;
    const int gb = (N + 63) / 64;
    const int nb = gN;
    const int gAF = (N + 31) / 32;   // final agg: 32 nodes/block

    // CSR build (once, shared by all 3 layers)
    k_zero_int<<<gN, 256, 0, stream>>>(cnt, N);
    k_count<<<gE, 256, 0, stream>>>(dstv, cnt, E);
    k_norms<<<gN, 256, 0, stream>>>(cnt, rsd, N);
    k_scan_block<<<nb, 256, 0, stream>>>(cnt, rowptr, bsum, N);
    k_scan_bsums<<<1, 256, 0, stream>>>(bsum, nb);
    k_scan_add<<<gN, 256, 0, stream>>>(rowptr, cursor, bsum, N, E);
    k_fill<<<gE, 256, 0, stream>>>(srcv, dstv, cursor, col, E);

    // layer 1 GEMM: x @ W1 -> Hb1
    k_gemm1<128><<<gb, 256, 0, stream>>>(x, W1, rsd, Hb1, N);
    // agg(layer1, relu, b1) fused with GEMM @ W2 -> Hb2
    k_agg_gemm<128><<<gb, 256, 0, stream>>>(Hb1, rowptr, col, rsd, b1, W2, Hb2, N);
    // agg(layer2, relu, b2) fused with GEMM @ W3 -> Hb3
    k_agg_gemm<64><<<gb, 256, 0, stream>>>(Hb2, rowptr, col, rsd, b2, W3, Hb3, N);
    // final aggregation + b3 -> d_out
    k_agg_final<64><<<gAF, 256, 0, stream>>>(Hb3, rowptr, col, rsd, b3, out, N);
}

// Round 5
// 299.890 us; speedup vs baseline: 1.1657x; 1.1657x over previous
//
#include <hip/hip_runtime.h>

// GCN 3-layer forward on MI355X — round 5: separate kernels, all-bf16 pipeline.
//
// R4 post-mortem: fusing agg+GEMM cost 4x occupancy (51KB LDS -> 15%) and the
// latency-bound gather collapsed to 0.9 TB/s. This round un-fuses (gathers run
// LDS-free at ~60% occupancy) but keeps the invd=rsd^2 identity: no f32
// partial buffer, activations flow as bf16.
//   k_gemm1:   x(f32) @ W1 -> Hb1 = bf16(H*rsd)
//   k_agg_bf:  Ab = bf16(relu(b + rsd*(Hb_self + sum Hb[col])))    [no LDS]
//   k_gemm_bf: Ab(bf16) @ W -> Hb_next
//   k_agg_final: f32 d_out

#define K_DIM 128

__device__ __forceinline__ unsigned short f2bf(float x) {
    unsigned u = __float_as_uint(x);
    return (unsigned short)((u + 0x7fffu + ((u >> 16) & 1u)) >> 16);
}
__device__ __forceinline__ float bflo(unsigned v) { return __uint_as_float(v << 16); }
__device__ __forceinline__ float bfhi(unsigned v) { return __uint_as_float(v & 0xffff0000u); }

// ---------------- degree / CSR build ----------------

__global__ void k_zero_int(int* __restrict__ p, int n) {
    int i = blockIdx.x * 256 + threadIdx.x;
    if (i < n) p[i] = 0;
}

__global__ void k_count(const int* __restrict__ dst, int* __restrict__ cnt, int E) {
    int e = blockIdx.x * 256 + threadIdx.x;
    if (e < E) atomicAdd(&cnt[dst[e]], 1);
}

__global__ void k_norms(const int* __restrict__ cnt, float* __restrict__ rsd, int n) {
    int i = blockIdx.x * 256 + threadIdx.x;
    if (i < n) rsd[i] = rsqrtf((float)cnt[i] + 1.0f);   // +1 self-loop
}

__global__ void k_scan_block(const int* __restrict__ cnt, int* __restrict__ rowptr,
                             int* __restrict__ bsum, int n) {
    __shared__ int s[256];
    int t = threadIdx.x;
    int i = blockIdx.x * 256 + t;
    int x = (i < n) ? cnt[i] : 0;
    s[t] = x;
    __syncthreads();
#pragma unroll
    for (int d = 1; d < 256; d <<= 1) {
        int v = (t >= d) ? s[t - d] : 0;
        __syncthreads();
        s[t] += v;
        __syncthreads();
    }
    if (i < n) rowptr[i] = s[t] - x;        // exclusive
    if (t == 255) bsum[blockIdx.x] = s[255];
}

__global__ void k_scan_bsums(int* __restrict__ bsum, int nb) {
    __shared__ int s[256];
    int t = threadIdx.x;
    int x = (t < nb) ? bsum[t] : 0;
    s[t] = x;
    __syncthreads();
#pragma unroll
    for (int d = 1; d < 256; d <<= 1) {
        int v = (t >= d) ? s[t - d] : 0;
        __syncthreads();
        s[t] += v;
        __syncthreads();
    }
    if (t < nb) bsum[t] = s[t] - x;         // exclusive
}

__global__ void k_scan_add(int* __restrict__ rowptr, int* __restrict__ cursor,
                           const int* __restrict__ bsum, int n, int E) {
    int i = blockIdx.x * 256 + threadIdx.x;
    if (i < n) {
        int v = rowptr[i] + bsum[i >> 8];
        rowptr[i] = v;
        cursor[i] = v;
    }
    if (i == 0) rowptr[n] = E;
}

__global__ void k_fill(const int* __restrict__ src, const int* __restrict__ dst,
                       int* __restrict__ cursor, int* __restrict__ col, int E) {
    int e = blockIdx.x * 256 + threadIdx.x;
    if (e < E) {
        int d = dst[e];
        int pos = atomicAdd(&cursor[d], 1);
        col[pos] = src[e];
    }
}

// ---------------- GEMM1: f32 X @ W -> Hb = bf16(H * rsd) ----------------
template <int COUT>
__launch_bounds__(256)
__global__ void k_gemm1(const float* __restrict__ X, const float* __restrict__ W,
                        const float* __restrict__ rsd,
                        unsigned short* __restrict__ Hb, int nrows) {
    constexpr int BM = 64, BK = 32, TN = 4;
    constexpr int CG = COUT / TN;
    constexpr int RG = 256 / CG;
    constexpr int TM = BM / RG;
    constexpr int BMP = 68;

    __shared__ float Xs[BK][BMP];
    __shared__ float Ws[BK][COUT];

    const int tid = threadIdx.x;
    const int tx = tid % CG;
    const int ty = tid / CG;
    const int r0 = blockIdx.x * BM;

    float acc[TM][TN];
#pragma unroll
    for (int i = 0; i < TM; ++i)
#pragma unroll
        for (int j = 0; j < TN; ++j) acc[i][j] = 0.0f;

    for (int kb = 0; kb < K_DIM; kb += BK) {
        __syncthreads();
        {
            int r = tid >> 3, kq = tid & 7;
#pragma unroll
            for (int p = 0; p < 2; ++p) {
                int rr = r + p * 32;
                int grow = r0 + rr;
                if (grow >= nrows) grow = nrows - 1;
                float4 v = *(const float4*)&X[(size_t)grow * K_DIM + kb + kq * 4];
                Xs[kq * 4 + 0][rr] = v.x;
                Xs[kq * 4 + 1][rr] = v.y;
                Xs[kq * 4 + 2][rr] = v.z;
                Xs[kq * 4 + 3][rr] = v.w;
            }
        }
        {
            constexpr int F4 = COUT / 4;
            constexpr int RP = 256 / F4;
            int wq = tid % F4, wr = tid / F4;
#pragma unroll
            for (int p = 0; p < BK / RP; ++p) {
                int krow = wr + p * RP;
                *(float4*)&Ws[krow][wq * 4] =
                    *(const float4*)&W[(size_t)(kb + krow) * COUT + wq * 4];
            }
        }
        __syncthreads();
#pragma unroll
        for (int kk = 0; kk < BK; ++kk) {
            float4 w4 = *(const float4*)&Ws[kk][tx * TN];
            float a[TM];
#pragma unroll
            for (int i = 0; i < TM; i += 4) {
                float4 a4 = *(const float4*)&Xs[kk][ty * TM + i];
                a[i] = a4.x; a[i + 1] = a4.y; a[i + 2] = a4.z; a[i + 3] = a4.w;
            }
#pragma unroll
            for (int i = 0; i < TM; ++i) {
                acc[i][0] += a[i] * w4.x;
                acc[i][1] += a[i] * w4.y;
                acc[i][2] += a[i] * w4.z;
                acc[i][3] += a[i] * w4.w;
            }
        }
    }

#pragma unroll
    for (int i = 0; i < TM; ++i) {
        int row = r0 + ty * TM + i;
        if (row < nrows) {
            float rs = rsd[row];
            ushort4 hb;
            hb.x = f2bf(acc[i][0] * rs);
            hb.y = f2bf(acc[i][1] * rs);
            hb.z = f2bf(acc[i][2] * rs);
            hb.w = f2bf(acc[i][3] * rs);
            *(ushort4*)&Hb[(size_t)row * COUT + tx * TN] = hb;
        }
    }
}

// ---------------- GEMM (bf16 activations): Ab @ W -> Hb = bf16(H * rsd) ----
template <int COUT>
__launch_bounds__(256)
__global__ void k_gemm_bf(const unsigned short* __restrict__ Ab, const float* __restrict__ W,
                          const float* __restrict__ rsd,
                          unsigned short* __restrict__ Hb, int nrows) {
    constexpr int BM = 64, BK = 32, TN = 4;
    constexpr int CG = COUT / TN;
    constexpr int RG = 256 / CG;
    constexpr int TM = BM / RG;
    constexpr int BMP = 68;

    __shared__ float Xs[BK][BMP];
    __shared__ float Ws[BK][COUT];

    const int tid = threadIdx.x;
    const int tx = tid % CG;
    const int ty = tid / CG;
    const int r0 = blockIdx.x * BM;

    float acc[TM][TN];
#pragma unroll
    for (int i = 0; i < TM; ++i)
#pragma unroll
        for (int j = 0; j < TN; ++j) acc[i][j] = 0.0f;

    for (int kb = 0; kb < K_DIM; kb += BK) {
        __syncthreads();
        {
            // 64 rows x 32 k of bf16: one uint4 (8 ch) per thread.
            int r = tid >> 2, kq = tid & 3;
            int grow = r0 + r;
            if (grow >= nrows) grow = nrows - 1;
            uint4 v = *(const uint4*)&Ab[(size_t)grow * K_DIM + kb + kq * 8];
            int k0 = kq * 8;
            Xs[k0 + 0][r] = bflo(v.x); Xs[k0 + 1][r] = bfhi(v.x);
            Xs[k0 + 2][r] = bflo(v.y); Xs[k0 + 3][r] = bfhi(v.y);
            Xs[k0 + 4][r] = bflo(v.z); Xs[k0 + 5][r] = bfhi(v.z);
            Xs[k0 + 6][r] = bflo(v.w); Xs[k0 + 7][r] = bfhi(v.w);
        }
        {
            constexpr int F4 = COUT / 4;
            constexpr int RP = 256 / F4;
            int wq = tid % F4, wr = tid / F4;
#pragma unroll
            for (int p = 0; p < BK / RP; ++p) {
                int krow = wr + p * RP;
                *(float4*)&Ws[krow][wq * 4] =
                    *(const float4*)&W[(size_t)(kb + krow) * COUT + wq * 4];
            }
        }
        __syncthreads();
#pragma unroll
        for (int kk = 0; kk < BK; ++kk) {
            float4 w4 = *(const float4*)&Ws[kk][tx * TN];
            float a[TM];
#pragma unroll
            for (int i = 0; i < TM; i += 4) {
                float4 a4 = *(const float4*)&Xs[kk][ty * TM + i];
                a[i] = a4.x; a[i + 1] = a4.y; a[i + 2] = a4.z; a[i + 3] = a4.w;
            }
#pragma unroll
            for (int i = 0; i < TM; ++i) {
                acc[i][0] += a[i] * w4.x;
                acc[i][1] += a[i] * w4.y;
                acc[i][2] += a[i] * w4.z;
                acc[i][3] += a[i] * w4.w;
            }
        }
    }

#pragma unroll
    for (int i = 0; i < TM; ++i) {
        int row = r0 + ty * TM + i;
        if (row < nrows) {
            float rs = rsd[row];
            ushort4 hb;
            hb.x = f2bf(acc[i][0] * rs);
            hb.y = f2bf(acc[i][1] * rs);
            hb.z = f2bf(acc[i][2] * rs);
            hb.w = f2bf(acc[i][3] * rs);
            *(ushort4*)&Hb[(size_t)row * COUT + tx * TN] = hb;
        }
    }
}

// ---------------- aggregation -> bf16 activations (LDS-free) ----------------
// Ab[i,:] = bf16(relu(bias + rsd[i]*(Hb[i,:] + sum_e Hb[col,:])))
template <int C>
__launch_bounds__(256)
__global__ void k_agg_bf(const unsigned short* __restrict__ Hb,
                         const int* __restrict__ rowptr, const int* __restrict__ col,
                         const float* __restrict__ rsd, const float* __restrict__ bias,
                         unsigned short* __restrict__ Ab, int n) {
    constexpr int TPN = C / 8;            // 16 (C=128)
    constexpr int NPB = 256 / TPN;
    const int node = blockIdx.x * NPB + threadIdx.x / TPN;
    const int c = (threadIdx.x % TPN) * 8;
    if (node >= n) return;

    float acc[8];
    {   // self-loop contribution
        uint4 v = *(const uint4*)&Hb[(size_t)node * C + c];
        acc[0] = bflo(v.x); acc[1] = bfhi(v.x);
        acc[2] = bflo(v.y); acc[3] = bfhi(v.y);
        acc[4] = bflo(v.z); acc[5] = bfhi(v.z);
        acc[6] = bflo(v.w); acc[7] = bfhi(v.w);
    }
    int e = rowptr[node], end = rowptr[node + 1];
    for (; e + 1 < end; e += 2) {
        int s0 = col[e], s1 = col[e + 1];
        uint4 v0 = *(const uint4*)&Hb[(size_t)s0 * C + c];
        uint4 v1 = *(const uint4*)&Hb[(size_t)s1 * C + c];
        acc[0] += bflo(v0.x); acc[1] += bfhi(v0.x);
        acc[2] += bflo(v0.y); acc[3] += bfhi(v0.y);
        acc[4] += bflo(v0.z); acc[5] += bfhi(v0.z);
        acc[6] += bflo(v0.w); acc[7] += bfhi(v0.w);
        acc[0] += bflo(v1.x); acc[1] += bfhi(v1.x);
        acc[2] += bflo(v1.y); acc[3] += bfhi(v1.y);
        acc[4] += bflo(v1.z); acc[5] += bfhi(v1.z);
        acc[6] += bflo(v1.w); acc[7] += bfhi(v1.w);
    }
    if (e < end) {
        int s0 = col[e];
        uint4 v0 = *(const uint4*)&Hb[(size_t)s0 * C + c];
        acc[0] += bflo(v0.x); acc[1] += bfhi(v0.x);
        acc[2] += bflo(v0.y); acc[3] += bfhi(v0.y);
        acc[4] += bflo(v0.z); acc[5] += bfhi(v0.z);
        acc[6] += bflo(v0.w); acc[7] += bfhi(v0.w);
    }

    const float rs = rsd[node];
    const float4 b0 = *(const float4*)&bias[c];
    const float4 b1 = *(const float4*)&bias[c + 4];
    float r[8];
    r[0] = fmaxf(b0.x + rs * acc[0], 0.0f); r[1] = fmaxf(b0.y + rs * acc[1], 0.0f);
    r[2] = fmaxf(b0.z + rs * acc[2], 0.0f); r[3] = fmaxf(b0.w + rs * acc[3], 0.0f);
    r[4] = fmaxf(b1.x + rs * acc[4], 0.0f); r[5] = fmaxf(b1.y + rs * acc[5], 0.0f);
    r[6] = fmaxf(b1.z + rs * acc[6], 0.0f); r[7] = fmaxf(b1.w + rs * acc[7], 0.0f);

    uint4 o;
    o.x = (unsigned)f2bf(r[0]) | ((unsigned)f2bf(r[1]) << 16);
    o.y = (unsigned)f2bf(r[2]) | ((unsigned)f2bf(r[3]) << 16);
    o.z = (unsigned)f2bf(r[4]) | ((unsigned)f2bf(r[5]) << 16);
    o.w = (unsigned)f2bf(r[6]) | ((unsigned)f2bf(r[7]) << 16);
    *(uint4*)&Ab[(size_t)node * C + c] = o;
}

// ---------------- final aggregation (layer 3) -> f32 d_out ----------------
template <int C>
__launch_bounds__(256)
__global__ void k_agg_final(const unsigned short* __restrict__ Hb,
                            const int* __restrict__ rowptr, const int* __restrict__ col,
                            const float* __restrict__ rsd, const float* __restrict__ bias,
                            float* __restrict__ OUT, int n) {
    constexpr int TPN = C / 8;            // 8 (C=64)
    constexpr int NPB = 256 / TPN;        // 32 nodes/block
    const int node = blockIdx.x * NPB + threadIdx.x / TPN;
    const int c = (threadIdx.x % TPN) * 8;
    if (node >= n) return;

    float acc[8];
    {   // self
        uint4 v = *(const uint4*)&Hb[(size_t)node * C + c];
        acc[0] = bflo(v.x); acc[1] = bfhi(v.x);
        acc[2] = bflo(v.y); acc[3] = bfhi(v.y);
        acc[4] = bflo(v.z); acc[5] = bfhi(v.z);
        acc[6] = bflo(v.w); acc[7] = bfhi(v.w);
    }
    int e = rowptr[node], end = rowptr[node + 1];
    for (; e + 1 < end; e += 2) {
        int s0 = col[e], s1 = col[e + 1];
        uint4 v0 = *(const uint4*)&Hb[(size_t)s0 * C + c];
        uint4 v1 = *(const uint4*)&Hb[(size_t)s1 * C + c];
        acc[0] += bflo(v0.x); acc[1] += bfhi(v0.x);
        acc[2] += bflo(v0.y); acc[3] += bfhi(v0.y);
        acc[4] += bflo(v0.z); acc[5] += bfhi(v0.z);
        acc[6] += bflo(v0.w); acc[7] += bfhi(v0.w);
        acc[0] += bflo(v1.x); acc[1] += bfhi(v1.x);
        acc[2] += bflo(v1.y); acc[3] += bfhi(v1.y);
        acc[4] += bflo(v1.z); acc[5] += bfhi(v1.z);
        acc[6] += bflo(v1.w); acc[7] += bfhi(v1.w);
    }
    if (e < end) {
        int s0 = col[e];
        uint4 v0 = *(const uint4*)&Hb[(size_t)s0 * C + c];
        acc[0] += bflo(v0.x); acc[1] += bfhi(v0.x);
        acc[2] += bflo(v0.y); acc[3] += bfhi(v0.y);
        acc[4] += bflo(v0.z); acc[5] += bfhi(v0.z);
        acc[6] += bflo(v0.w); acc[7] += bfhi(v0.w);
    }

    const float rs = rsd[node];
    const float4 b0 = *(const float4*)&bias[c];
    const float4 b1 = *(const float4*)&bias[c + 4];
    float* po = &OUT[(size_t)node * C + c];
    *(float4*)&po[0] = make_float4(b0.x + rs * acc[0], b0.y + rs * acc[1],
                                   b0.z + rs * acc[2], b0.w + rs * acc[3]);
    *(float4*)&po[4] = make_float4(b1.x + rs * acc[4], b1.y + rs * acc[5],
                                   b1.z + rs * acc[6], b1.w + rs * acc[7]);
}

// ---------------- launch ----------------

extern "C" void kernel_launch(void* const* d_in, const int* in_sizes, int n_in,
                              void* d_out, int out_size, void* d_ws, size_t ws_size,
                              hipStream_t stream) {
    const float* x  = (const float*)d_in[0];
    const int*   ei = (const int*)d_in[1];
    const float* W1 = (const float*)d_in[2];
    const float* b1 = (const float*)d_in[3];
    const float* W2 = (const float*)d_in[4];
    const float* b2 = (const float*)d_in[5];
    const float* W3 = (const float*)d_in[6];
    const float* b3 = (const float*)d_in[7];

    const int N = in_sizes[0] / K_DIM;   // 50000
    const int E = in_sizes[1] / 2;       // 640000
    const int* srcv = ei;
    const int* dstv = ei + E;

    char* ws = (char*)d_ws;
    size_t off = 0;
    auto alloc = [&](size_t bytes) {
        char* p = ws + off;
        off += (bytes + 255) & ~(size_t)255;
        return p;
    };
    int*   cnt    = (int*)alloc((size_t)N * 4);
    int*   rowptr = (int*)alloc((size_t)(N + 1) * 4);
    int*   cursor = (int*)alloc((size_t)N * 4);
    int*   bsum   = (int*)alloc(256 * 4);
    float* rsd    = (float*)alloc((size_t)N * 4);
    int*   col    = (int*)alloc((size_t)E * 4);
    unsigned short* Hb1 = (unsigned short*)alloc((size_t)N * 128 * 2);
    unsigned short* Ab  = (unsigned short*)alloc((size_t)N * 128 * 2);
    unsigned short* Hb3 = (unsigned short*)alloc((size_t)N * 64 * 2);
    float* out = (float*)d_out;

    const int gN = (N + 255) / 256;
    const int gE = (E + 255) / 256;
    const int gb = (N + 63) / 64;
    const int nb = gN;
    const int gA128 = (N + 15) / 16;   // k_agg_bf C=128: 16 nodes/block
    const int gAF   = (N + 31) / 32;   // final agg C=64: 32 nodes/block

    // CSR build (once, shared by all 3 layers)
    k_zero_int<<<gN, 256, 0, stream>>>(cnt, N);
    k_count<<<gE, 256, 0, stream>>>(dstv, cnt, E);
    k_norms<<<gN, 256, 0, stream>>>(cnt, rsd, N);
    k_scan_block<<<nb, 256, 0, stream>>>(cnt, rowptr, bsum, N);
    k_scan_bsums<<<1, 256, 0, stream>>>(bsum, nb);
    k_scan_add<<<gN, 256, 0, stream>>>(rowptr, cursor, bsum, N, E);
    k_fill<<<gE, 256, 0, stream>>>(srcv, dstv, cursor, col, E);

    // layer 1: x @ W1 -> Hb1; agg -> Ab (bf16 activations)
    k_gemm1<128><<<gb, 256, 0, stream>>>(x, W1, rsd, Hb1, N);
    k_agg_bf<128><<<gA128, 256, 0, stream>>>(Hb1, rowptr, col, rsd, b1, Ab, N);

    // layer 2: Ab @ W2 -> Hb1 (reuse); agg -> Ab
    k_gemm_bf<128><<<gb, 256, 0, stream>>>(Ab, W2, rsd, Hb1, N);
    k_agg_bf<128><<<gA128, 256, 0, stream>>>(Hb1, rowptr, col, rsd, b2, Ab, N);

    // layer 3: Ab @ W3 -> Hb3; final agg -> d_out
    k_gemm_bf<64><<<gb, 256, 0, stream>>>(Ab, W3, rsd, Hb3, N);
    k_agg_final<64><<<gAF, 256, 0, stream>>>(Hb3, rowptr, col, rsd, b3, out, N);
}

// Round 6
// 288.505 us; speedup vs baseline: 1.2117x; 1.0395x over previous
//
#include <hip/hip_runtime.h>

// GCN 3-layer forward on MI355X — round 6: MFMA bf16 GEMMs.
//
// R5 post-mortem: pipeline at 300 us; gathers are fabric-bound (~67 us, hard),
// f32 vector GEMMs ~60-70 us. This round moves GEMMs to matrix cores:
//   k_cvt:       x -> bf16 Xb; W1/2/3 -> bf16 transposed Wt (COUT x 128)
//   k_gemm_mfma: LDS-free, 4 waves/block, wave = 16 rows x COUT cols,
//                v_mfma_f32_16x16x32_bf16, epilogue *rsd -> bf16 Hb
//   k_agg_bf / k_agg_final: unchanged (proven, occupancy ~60%)
// k_norms merged into k_scan_block (-1 dispatch).

#define K_DIM 128

typedef __attribute__((ext_vector_type(8))) short bf16x8;
typedef __attribute__((ext_vector_type(4))) float f32x4;

__device__ __forceinline__ unsigned short f2bf(float x) {
    unsigned u = __float_as_uint(x);
    return (unsigned short)((u + 0x7fffu + ((u >> 16) & 1u)) >> 16);
}
__device__ __forceinline__ float bflo(unsigned v) { return __uint_as_float(v << 16); }
__device__ __forceinline__ float bfhi(unsigned v) { return __uint_as_float(v & 0xffff0000u); }

// ---------------- degree / CSR build ----------------

__global__ void k_zero_int(int* __restrict__ p, int n) {
    int i = blockIdx.x * 256 + threadIdx.x;
    if (i < n) p[i] = 0;
}

__global__ void k_count(const int* __restrict__ dst, int* __restrict__ cnt, int E) {
    int e = blockIdx.x * 256 + threadIdx.x;
    if (e < E) atomicAdd(&cnt[dst[e]], 1);
}

// block-wise scan of cnt -> exclusive prefix in rowptr, block total in bsum.
// Also computes rsd = rsqrt(cnt+1) (merged from old k_norms).
__global__ void k_scan_block(const int* __restrict__ cnt, int* __restrict__ rowptr,
                             int* __restrict__ bsum, float* __restrict__ rsd, int n) {
    __shared__ int s[256];
    int t = threadIdx.x;
    int i = blockIdx.x * 256 + t;
    int x = (i < n) ? cnt[i] : 0;
    if (i < n) rsd[i] = rsqrtf((float)x + 1.0f);
    s[t] = x;
    __syncthreads();
#pragma unroll
    for (int d = 1; d < 256; d <<= 1) {
        int v = (t >= d) ? s[t - d] : 0;
        __syncthreads();
        s[t] += v;
        __syncthreads();
    }
    if (i < n) rowptr[i] = s[t] - x;        // exclusive
    if (t == 255) bsum[blockIdx.x] = s[255];
}

__global__ void k_scan_bsums(int* __restrict__ bsum, int nb) {
    __shared__ int s[256];
    int t = threadIdx.x;
    int x = (t < nb) ? bsum[t] : 0;
    s[t] = x;
    __syncthreads();
#pragma unroll
    for (int d = 1; d < 256; d <<= 1) {
        int v = (t >= d) ? s[t - d] : 0;
        __syncthreads();
        s[t] += v;
        __syncthreads();
    }
    if (t < nb) bsum[t] = s[t] - x;         // exclusive
}

__global__ void k_scan_add(int* __restrict__ rowptr, int* __restrict__ cursor,
                           const int* __restrict__ bsum, int n, int E) {
    int i = blockIdx.x * 256 + threadIdx.x;
    if (i < n) {
        int v = rowptr[i] + bsum[i >> 8];
        rowptr[i] = v;
        cursor[i] = v;
    }
    if (i == 0) rowptr[n] = E;
}

__global__ void k_fill(const int* __restrict__ src, const int* __restrict__ dst,
                       int* __restrict__ cursor, int* __restrict__ col, int E) {
    int e = blockIdx.x * 256 + threadIdx.x;
    if (e < E) {
        int d = dst[e];
        int pos = atomicAdd(&cursor[d], 1);
        col[pos] = src[e];
    }
}

// ---------------- conversions: x->bf16, W->bf16 transposed ----------------
// Section 0: Xb[i] = bf16(x[i])                (nx4 threads, 4 elems each)
// Sections 1-3: Wt[n*128+k] = bf16(W[k*COUT+n])
__global__ void k_cvt(const float* __restrict__ x, unsigned short* __restrict__ Xb,
                      const float* __restrict__ W1, const float* __restrict__ W2,
                      const float* __restrict__ W3,
                      unsigned short* __restrict__ Wt1, unsigned short* __restrict__ Wt2,
                      unsigned short* __restrict__ Wt3, int nx4) {
    int i = blockIdx.x * 256 + threadIdx.x;
    if (i < nx4) {
        float4 v = *(const float4*)&x[(size_t)i * 4];
        ushort4 o;
        o.x = f2bf(v.x); o.y = f2bf(v.y); o.z = f2bf(v.z); o.w = f2bf(v.w);
        *(ushort4*)&Xb[(size_t)i * 4] = o;
        return;
    }
    int j = i - nx4;
    if (j < 16384) { int n = j >> 7, k = j & 127; Wt1[n * 128 + k] = f2bf(W1[k * 128 + n]); return; }
    j -= 16384;
    if (j < 16384) { int n = j >> 7, k = j & 127; Wt2[n * 128 + k] = f2bf(W2[k * 128 + n]); return; }
    j -= 16384;
    if (j < 8192)  { int n = j >> 7, k = j & 127; Wt3[n * 128 + k] = f2bf(W3[k * 64 + n]); return; }
}

// ---------------- MFMA GEMM: Hb = bf16((A @ W) * rsd) ----------------
// A: [nrows,128] bf16 row-major. Wt: [COUT,128] bf16 (= W^T). LDS-free.
// 4 waves/block; wave computes 16 rows x COUT cols via 16x16x32 bf16 MFMA.
// Fragment layouts (learn_hip verified): A/B lane m(or n)=lane&15, 8 k-elems at
// k = kb*32 + (lane>>4)*8; C/D col=lane&15, row=(lane>>4)*4+reg.
template <int COUT>
__launch_bounds__(256)
__global__ void k_gemm_mfma(const unsigned short* __restrict__ A,
                            const unsigned short* __restrict__ Wt,
                            const float* __restrict__ rsd,
                            unsigned short* __restrict__ Hb, int nrows) {
    constexpr int NT = COUT / 16;
    const int wave = threadIdx.x >> 6;
    const int lane = threadIdx.x & 63;
    const int m16 = lane & 15;
    const int kg  = lane >> 4;                 // 0..3
    const int r0w = blockIdx.x * 64 + wave * 16;

    int arow = r0w + m16;
    if (arow >= nrows) arow = nrows - 1;       // clamp; stores guarded

    bf16x8 a[4];
#pragma unroll
    for (int kb = 0; kb < 4; ++kb)
        a[kb] = *(const bf16x8*)&A[(size_t)arow * 128 + kb * 32 + kg * 8];

    f32x4 acc[NT];
#pragma unroll
    for (int t = 0; t < NT; ++t) acc[t] = (f32x4){0.f, 0.f, 0.f, 0.f};

#pragma unroll
    for (int t = 0; t < NT; ++t) {
        const unsigned short* wp = &Wt[(size_t)(t * 16 + m16) * 128 + kg * 8];
#pragma unroll
        for (int kb = 0; kb < 4; ++kb) {
            bf16x8 b = *(const bf16x8*)&wp[kb * 32];
            acc[t] = __builtin_amdgcn_mfma_f32_16x16x32_bf16(a[kb], b, acc[t], 0, 0, 0);
        }
    }

    const int rowb = r0w + kg * 4;
    float rs[4];
#pragma unroll
    for (int i = 0; i < 4; ++i)
        rs[i] = (rowb + i < nrows) ? rsd[rowb + i] : 0.0f;

#pragma unroll
    for (int t = 0; t < NT; ++t) {
#pragma unroll
        for (int i = 0; i < 4; ++i) {
            int r = rowb + i;
            if (r < nrows)
                Hb[(size_t)r * COUT + t * 16 + m16] = f2bf(acc[t][i] * rs[i]);
        }
    }
}

// ---------------- aggregation -> bf16 activations (LDS-free) ----------------
// Ab[i,:] = bf16(relu(bias + rsd[i]*(Hb[i,:] + sum_e Hb[col,:])))
template <int C>
__launch_bounds__(256)
__global__ void k_agg_bf(const unsigned short* __restrict__ Hb,
                         const int* __restrict__ rowptr, const int* __restrict__ col,
                         const float* __restrict__ rsd, const float* __restrict__ bias,
                         unsigned short* __restrict__ Ab, int n) {
    constexpr int TPN = C / 8;
    constexpr int NPB = 256 / TPN;
    const int node = blockIdx.x * NPB + threadIdx.x / TPN;
    const int c = (threadIdx.x % TPN) * 8;
    if (node >= n) return;

    float acc[8];
    {   // self-loop contribution
        uint4 v = *(const uint4*)&Hb[(size_t)node * C + c];
        acc[0] = bflo(v.x); acc[1] = bfhi(v.x);
        acc[2] = bflo(v.y); acc[3] = bfhi(v.y);
        acc[4] = bflo(v.z); acc[5] = bfhi(v.z);
        acc[6] = bflo(v.w); acc[7] = bfhi(v.w);
    }
    int e = rowptr[node], end = rowptr[node + 1];
    for (; e + 1 < end; e += 2) {
        int s0 = col[e], s1 = col[e + 1];
        uint4 v0 = *(const uint4*)&Hb[(size_t)s0 * C + c];
        uint4 v1 = *(const uint4*)&Hb[(size_t)s1 * C + c];
        acc[0] += bflo(v0.x); acc[1] += bfhi(v0.x);
        acc[2] += bflo(v0.y); acc[3] += bfhi(v0.y);
        acc[4] += bflo(v0.z); acc[5] += bfhi(v0.z);
        acc[6] += bflo(v0.w); acc[7] += bfhi(v0.w);
        acc[0] += bflo(v1.x); acc[1] += bfhi(v1.x);
        acc[2] += bflo(v1.y); acc[3] += bfhi(v1.y);
        acc[4] += bflo(v1.z); acc[5] += bfhi(v1.z);
        acc[6] += bflo(v1.w); acc[7] += bfhi(v1.w);
    }
    if (e < end) {
        int s0 = col[e];
        uint4 v0 = *(const uint4*)&Hb[(size_t)s0 * C + c];
        acc[0] += bflo(v0.x); acc[1] += bfhi(v0.x);
        acc[2] += bflo(v0.y); acc[3] += bfhi(v0.y);
        acc[4] += bflo(v0.z); acc[5] += bfhi(v0.z);
        acc[6] += bflo(v0.w); acc[7] += bfhi(v0.w);
    }

    const float rs = rsd[node];
    const float4 b0 = *(const float4*)&bias[c];
    const float4 b1 = *(const float4*)&bias[c + 4];
    float r[8];
    r[0] = fmaxf(b0.x + rs * acc[0], 0.0f); r[1] = fmaxf(b0.y + rs * acc[1], 0.0f);
    r[2] = fmaxf(b0.z + rs * acc[2], 0.0f); r[3] = fmaxf(b0.w + rs * acc[3], 0.0f);
    r[4] = fmaxf(b1.x + rs * acc[4], 0.0f); r[5] = fmaxf(b1.y + rs * acc[5], 0.0f);
    r[6] = fmaxf(b1.z + rs * acc[6], 0.0f); r[7] = fmaxf(b1.w + rs * acc[7], 0.0f);

    uint4 o;
    o.x = (unsigned)f2bf(r[0]) | ((unsigned)f2bf(r[1]) << 16);
    o.y = (unsigned)f2bf(r[2]) | ((unsigned)f2bf(r[3]) << 16);
    o.z = (unsigned)f2bf(r[4]) | ((unsigned)f2bf(r[5]) << 16);
    o.w = (unsigned)f2bf(r[6]) | ((unsigned)f2bf(r[7]) << 16);
    *(uint4*)&Ab[(size_t)node * C + c] = o;
}

// ---------------- final aggregation (layer 3) -> f32 d_out ----------------
template <int C>
__launch_bounds__(256)
__global__ void k_agg_final(const unsigned short* __restrict__ Hb,
                            const int* __restrict__ rowptr, const int* __restrict__ col,
                            const float* __restrict__ rsd, const float* __restrict__ bias,
                            float* __restrict__ OUT, int n) {
    constexpr int TPN = C / 8;
    constexpr int NPB = 256 / TPN;
    const int node = blockIdx.x * NPB + threadIdx.x / TPN;
    const int c = (threadIdx.x % TPN) * 8;
    if (node >= n) return;

    float acc[8];
    {   // self
        uint4 v = *(const uint4*)&Hb[(size_t)node * C + c];
        acc[0] = bflo(v.x); acc[1] = bfhi(v.x);
        acc[2] = bflo(v.y); acc[3] = bfhi(v.y);
        acc[4] = bflo(v.z); acc[5] = bfhi(v.z);
        acc[6] = bflo(v.w); acc[7] = bfhi(v.w);
    }
    int e = rowptr[node], end = rowptr[node + 1];
    for (; e + 1 < end; e += 2) {
        int s0 = col[e], s1 = col[e + 1];
        uint4 v0 = *(const uint4*)&Hb[(size_t)s0 * C + c];
        uint4 v1 = *(const uint4*)&Hb[(size_t)s1 * C + c];
        acc[0] += bflo(v0.x); acc[1] += bfhi(v0.x);
        acc[2] += bflo(v0.y); acc[3] += bfhi(v0.y);
        acc[4] += bflo(v0.z); acc[5] += bfhi(v0.z);
        acc[6] += bflo(v0.w); acc[7] += bfhi(v0.w);
        acc[0] += bflo(v1.x); acc[1] += bfhi(v1.x);
        acc[2] += bflo(v1.y); acc[3] += bfhi(v1.y);
        acc[4] += bflo(v1.z); acc[5] += bfhi(v1.z);
        acc[6] += bflo(v1.w); acc[7] += bfhi(v1.w);
    }
    if (e < end) {
        int s0 = col[e];
        uint4 v0 = *(const uint4*)&Hb[(size_t)s0 * C + c];
        acc[0] += bflo(v0.x); acc[1] += bfhi(v0.x);
        acc[2] += bflo(v0.y); acc[3] += bfhi(v0.y);
        acc[4] += bflo(v0.z); acc[5] += bfhi(v0.z);
        acc[6] += bflo(v0.w); acc[7] += bfhi(v0.w);
    }

    const float rs = rsd[node];
    const float4 b0 = *(const float4*)&bias[c];
    const float4 b1 = *(const float4*)&bias[c + 4];
    float* po = &OUT[(size_t)node * C + c];
    *(float4*)&po[0] = make_float4(b0.x + rs * acc[0], b0.y + rs * acc[1],
                                   b0.z + rs * acc[2], b0.w + rs * acc[3]);
    *(float4*)&po[4] = make_float4(b1.x + rs * acc[4], b1.y + rs * acc[5],
                                   b1.z + rs * acc[6], b1.w + rs * acc[7]);
}

// ---------------- launch ----------------

extern "C" void kernel_launch(void* const* d_in, const int* in_sizes, int n_in,
                              void* d_out, int out_size, void* d_ws, size_t ws_size,
                              hipStream_t stream) {
    const float* x  = (const float*)d_in[0];
    const int*   ei = (const int*)d_in[1];
    const float* W1 = (const float*)d_in[2];
    const float* b1 = (const float*)d_in[3];
    const float* W2 = (const float*)d_in[4];
    const float* b2 = (const float*)d_in[5];
    const float* W3 = (const float*)d_in[6];
    const float* b3 = (const float*)d_in[7];

    const int N = in_sizes[0] / K_DIM;   // 50000
    const int E = in_sizes[1] / 2;       // 640000
    const int* srcv = ei;
    const int* dstv = ei + E;

    char* ws = (char*)d_ws;
    size_t off = 0;
    auto alloc = [&](size_t bytes) {
        char* p = ws + off;
        off += (bytes + 255) & ~(size_t)255;
        return p;
    };
    int*   cnt    = (int*)alloc((size_t)N * 4);
    int*   rowptr = (int*)alloc((size_t)(N + 1) * 4);
    int*   cursor = (int*)alloc((size_t)N * 4);
    int*   bsum   = (int*)alloc(256 * 4);
    float* rsd    = (float*)alloc((size_t)N * 4);
    int*   col    = (int*)alloc((size_t)E * 4);
    unsigned short* Xb  = (unsigned short*)alloc((size_t)N * 128 * 2);
    unsigned short* Wt1 = (unsigned short*)alloc(128 * 128 * 2);
    unsigned short* Wt2 = (unsigned short*)alloc(128 * 128 * 2);
    unsigned short* Wt3 = (unsigned short*)alloc(64 * 128 * 2);
    unsigned short* Hb1 = (unsigned short*)alloc((size_t)N * 128 * 2);
    unsigned short* Ab  = (unsigned short*)alloc((size_t)N * 128 * 2);
    unsigned short* Hb2 = (unsigned short*)alloc((size_t)N * 128 * 2);
    unsigned short* Hb3 = (unsigned short*)alloc((size_t)N * 64 * 2);
    float* out = (float*)d_out;

    const int gN = (N + 255) / 256;
    const int gE = (E + 255) / 256;
    const int gb = (N + 63) / 64;
    const int nb = gN;
    const int gA128 = (N + 15) / 16;
    const int gAF   = (N + 31) / 32;
    const int nx4   = N * 32;                     // x float4 count
    const int gCVT  = (nx4 + 16384 + 16384 + 8192 + 255) / 256;

    // CSR build (once, shared by all 3 layers)
    k_zero_int<<<gN, 256, 0, stream>>>(cnt, N);
    k_count<<<gE, 256, 0, stream>>>(dstv, cnt, E);
    k_scan_block<<<nb, 256, 0, stream>>>(cnt, rowptr, bsum, rsd, N);
    k_scan_bsums<<<1, 256, 0, stream>>>(bsum, nb);
    k_scan_add<<<gN, 256, 0, stream>>>(rowptr, cursor, bsum, N, E);
    k_fill<<<gE, 256, 0, stream>>>(srcv, dstv, cursor, col, E);

    // conversions
    k_cvt<<<gCVT, 256, 0, stream>>>(x, Xb, W1, W2, W3, Wt1, Wt2, Wt3, nx4);

    // layer 1
    k_gemm_mfma<128><<<gb, 256, 0, stream>>>(Xb, Wt1, rsd, Hb1, N);
    k_agg_bf<128><<<gA128, 256, 0, stream>>>(Hb1, rowptr, col, rsd, b1, Ab, N);

    // layer 2
    k_gemm_mfma<128><<<gb, 256, 0, stream>>>(Ab, Wt2, rsd, Hb2, N);
    k_agg_bf<128><<<gA128, 256, 0, stream>>>(Hb2, rowptr, col, rsd, b2, Ab, N);

    // layer 3
    k_gemm_mfma<64><<<gb, 256, 0, stream>>>(Ab, Wt3, rsd, Hb3, N);
    k_agg_final<64><<<gAF, 256, 0, stream>>>(Hb3, rowptr, col, rsd, b3, out, N);
}